// Round 5
// baseline (377.292 us; speedup 1.0000x reference)
//
#include <hip/hip_runtime.h>
#include <math.h>

#define ROWS 2048
#define COLS 32768
#define TOPK 10

constexpr float INV_T  = 1.0f / 2.5f;
constexpr float EPS_F  = 1e-10f;

// native sigmoid(x / T): rcp + exp are the 1/4-rate transcendentals; accuracy
// ~1e-6 rel, far inside the ~2% harness threshold.
__device__ __forceinline__ float sigmoid_t(float x) {
    return __builtin_amdgcn_rcpf(1.0f + __expf(-x * INV_T));
}

// One block per row. 256 threads = 4 waves.
// Each thread: streaming float4 loads, running sigmoid-sum, register-resident
// sorted (descending) top-10 of the RAW values (monotone transform => same
// top-k set as s_soft). Then wave-level extraction (shfl max + ballot pick),
// then a 40-candidate final merge in wave 0.
__global__ __launch_bounds__(256, 4) void row_topk_kernel(
        const float* __restrict__ S, float* __restrict__ accum) {
    const int row  = blockIdx.x;
    const int tid  = threadIdx.x;
    const int lane = tid & 63;
    const int wid  = tid >> 6;

    __shared__ float cand[4 * TOPK];
    __shared__ float wsum[4];

    const float4* rowp = (const float4*)(S + (size_t)row * COLS);

    // top[0] = max ... top[TOPK-1] = min  (all indices compile-time constant)
    float top[TOPK];
#pragma unroll
    for (int i = 0; i < TOPK; ++i) top[i] = -INFINITY;

    float ssum = 0.0f;

    constexpr int ITERS = COLS / 4 / 256;   // 32
#pragma unroll 4
    for (int i = 0; i < ITERS; ++i) {
        float4 v = rowp[i * 256 + tid];
        float xs[4] = {v.x, v.y, v.z, v.w};
#pragma unroll
        for (int c = 0; c < 4; ++c) {
            float x = xs[c];
            ssum += sigmoid_t(x);
            if (x > top[TOPK - 1]) {
                top[TOPK - 1] = x;
                // one insertion pass restores descending order; fully static
#pragma unroll
                for (int j = TOPK - 1; j > 0; --j) {
                    float a = top[j - 1], b = top[j];
                    top[j - 1] = fmaxf(a, b);
                    top[j]     = fminf(a, b);
                }
            }
        }
    }

    // ---- wave reduce the sigmoid sum ----
#pragma unroll
    for (int off = 32; off >= 1; off >>= 1)
        ssum += __shfl_xor(ssum, off, 64);
    if (lane == 0) wsum[wid] = ssum;

    // ---- wave-level top-10 extraction (no barriers inside) ----
#pragma unroll
    for (int k = 0; k < TOPK; ++k) {
        float m = top[0];
#pragma unroll
        for (int off = 32; off >= 1; off >>= 1)
            m = fmaxf(m, __shfl_xor(m, off, 64));
        // remove exactly one copy: lowest lane holding the max
        unsigned long long b = __ballot(top[0] == m);
        int src = __ffsll(b) - 1;
        if (lane == src) {
#pragma unroll
            for (int j = 0; j < TOPK - 1; ++j) top[j] = top[j + 1];
            top[TOPK - 1] = -INFINITY;
        }
        if (lane == 0) cand[wid * TOPK + k] = m;
    }
    __syncthreads();

    // ---- final merge: 40 candidates -> global top-10, wave 0 only ----
    if (wid == 0) {
        float v = (lane < 4 * TOPK) ? cand[lane] : -INFINITY;
        float num = 0.0f;
#pragma unroll
        for (int k = 0; k < TOPK; ++k) {
            float m = v;
#pragma unroll
            for (int off = 32; off >= 1; off >>= 1)
                m = fmaxf(m, __shfl_xor(m, off, 64));
            unsigned long long b = __ballot(v == m);
            int src = __ffsll(b) - 1;
            if (lane == src) v = -INFINITY;
            num += sigmoid_t(m);   // uniform across lanes
        }
        if (lane == 0) {
            float den = wsum[0] + wsum[1] + wsum[2] + wsum[3];
            float stk = num / den;                       // sum_top_k for this row
            atomicAdd(accum, stk * __logf(stk + EPS_F)); // device-scope f32 atomic
        }
    }
}

__global__ void finalize_kernel(const float* __restrict__ accum,
                                float* __restrict__ out) {
    out[0] = -accum[0] * (1.0f / (float)ROWS);
}

extern "C" void kernel_launch(void* const* d_in, const int* in_sizes, int n_in,
                              void* d_out, int out_size, void* d_ws, size_t ws_size,
                              hipStream_t stream) {
    const float* S   = (const float*)d_in[0];
    float* out       = (float*)d_out;
    float* accum     = (float*)d_ws;

    // d_ws is re-poisoned to 0xAA before every launch — zero the accumulator.
    hipMemsetAsync(accum, 0, sizeof(float), stream);

    row_topk_kernel<<<ROWS, 256, 0, stream>>>(S, accum);
    finalize_kernel<<<1, 1, 0, stream>>>(accum, out);
}